// Round 9
// baseline (273.730 us; speedup 1.0000x reference)
//
#include <hip/hip_runtime.h>
#include <hip/hip_bf16.h>

#define N_NODES 100000
#define FIN 128
#define HID 16
#define NCLS 40
#define NEDGE 3200000
#define NBUCK 391     // ceil(100000/256): 256 dst-nodes per bucket
#define NCHUNK 782    // ceil(NEDGE/4096)
#define W_ROW 144     // swizzled W row stride (floats)
#define SCAP 12288    // sortB staged capacity (48KB); max bucket ~8.5K

typedef int v4i __attribute__((ext_vector_type(4)));

// f32 -> bf16 (RNE)
__device__ __forceinline__ unsigned short f2b(float f) {
  union { float f; unsigned u; } v;
  v.f = f;
  unsigned r = v.u + 0x7FFFu + ((v.u >> 16) & 1u);
  return (unsigned short)(r >> 16);
}

// accumulate 8 bf16 (one uint4 = 16B) into 8 fp32
__device__ __forceinline__ void accum8(uint4 w, float* a) {
  union { unsigned u; float f; } t;
  t.u = w.x << 16;         a[0] += t.f;
  t.u = w.x & 0xFFFF0000u; a[1] += t.f;
  t.u = w.y << 16;         a[2] += t.f;
  t.u = w.y & 0xFFFF0000u; a[3] += t.f;
  t.u = w.z << 16;         a[4] += t.f;
  t.u = w.z & 0xFFFF0000u; a[5] += t.f;
  t.u = w.w << 16;         a[6] += t.f;
  t.u = w.w & 0xFFFF0000u; a[7] += t.f;
}

// ---------------------------------------------------------------------------
// R16 proj1: 2 NODES PER THREAD. R8 counters showed proj1 is LDS-read-
// instruction bound (256 ds_read_b128/thread for 1 node; LDS pipe shared by
// 4 SIMDs ~= 31us). Each W read now feeds 2 FMA chains -> LDS insts per node
// halved, FMA ILP doubled. N even => one liveness flag per node pair.
// ---------------------------------------------------------------------------
__global__ __launch_bounds__(256) void proj1_kernel(
    const float* __restrict__ x, const float* __restrict__ W1,
    const float* __restrict__ root1,
    unsigned* __restrict__ xw1b, float* __restrict__ xr1) {
  __shared__ float Wl[32 * W_ROW];  // 18.4 KB

  int tid = threadIdx.x;
  for (int t = tid; t < 32 * FIN; t += 256) {
    int c = t >> 7, k = t & 127;
    float v = (c < 16) ? W1[FIN * HID + k * HID + c] : root1[k * HID + (c - 16)];
    Wl[c * W_ROW + k + ((k >> 5) << 2)] = v;
  }
  __syncthreads();

  int n0 = (blockIdx.x * 64 + (tid >> 2)) * 2;  // even; n1 = n0+1
  int j = tid & 3;
  bool live = (n0 < N_NODES);  // N even => n1 < N iff n0 < N

  float4 xa[8], xb[8];
  if (live) {
    const float4* pa = (const float4*)(x + (size_t)n0 * FIN + j * 32);
    const float4* pb = (const float4*)(x + (size_t)(n0 + 1) * FIN + j * 32);
#pragma unroll
    for (int m = 0; m < 8; ++m) {
      xa[m] = pa[m];
      xb[m] = pb[m];
    }
  } else {
#pragma unroll
    for (int m = 0; m < 8; ++m) {
      xa[m] = make_float4(0.f, 0.f, 0.f, 0.f);
      xb[m] = make_float4(0.f, 0.f, 0.f, 0.f);
    }
  }

  float aa[32], ab[32];
  const float* wj = Wl + j * 36;
#pragma unroll 4
  for (int c = 0; c < 32; ++c) {
    const float4* wr = (const float4*)(wj + c * W_ROW);
    float sa = 0.f, sb = 0.f;
#pragma unroll
    for (int m = 0; m < 8; ++m) {
      float4 wv = wr[m];
      sa += xa[m].x * wv.x + xa[m].y * wv.y + xa[m].z * wv.z + xa[m].w * wv.w;
      sb += xb[m].x * wv.x + xb[m].y * wv.y + xb[m].z * wv.z + xb[m].w * wv.w;
    }
    aa[c] = sa;
    ab[c] = sb;
  }

  // reduce the 4 k-quarters of each node (lanes differ in bits 0-1)
#pragma unroll
  for (int c = 0; c < 32; ++c) {
    aa[c] += __shfl_xor(aa[c], 1);
    aa[c] += __shfl_xor(aa[c], 2);
    ab[c] += __shfl_xor(ab[c], 1);
    ab[c] += __shfl_xor(ab[c], 2);
  }
  if (!live) return;

  if (j == 0) {
    uint4 pk;
    pk.x = (unsigned)f2b(aa[0]) | ((unsigned)f2b(aa[1]) << 16);
    pk.y = (unsigned)f2b(aa[2]) | ((unsigned)f2b(aa[3]) << 16);
    pk.z = (unsigned)f2b(aa[4]) | ((unsigned)f2b(aa[5]) << 16);
    pk.w = (unsigned)f2b(aa[6]) | ((unsigned)f2b(aa[7]) << 16);
    *(uint4*)((char*)xw1b + (size_t)n0 * 32) = pk;
    pk.x = (unsigned)f2b(ab[0]) | ((unsigned)f2b(ab[1]) << 16);
    pk.y = (unsigned)f2b(ab[2]) | ((unsigned)f2b(ab[3]) << 16);
    pk.z = (unsigned)f2b(ab[4]) | ((unsigned)f2b(ab[5]) << 16);
    pk.w = (unsigned)f2b(ab[6]) | ((unsigned)f2b(ab[7]) << 16);
    *(uint4*)((char*)xw1b + (size_t)(n0 + 1) * 32) = pk;
  } else if (j == 1) {
    uint4 pk;
    pk.x = (unsigned)f2b(aa[8]) | ((unsigned)f2b(aa[9]) << 16);
    pk.y = (unsigned)f2b(aa[10]) | ((unsigned)f2b(aa[11]) << 16);
    pk.z = (unsigned)f2b(aa[12]) | ((unsigned)f2b(aa[13]) << 16);
    pk.w = (unsigned)f2b(aa[14]) | ((unsigned)f2b(aa[15]) << 16);
    *(uint4*)((char*)xw1b + (size_t)n0 * 32 + 16) = pk;
    pk.x = (unsigned)f2b(ab[8]) | ((unsigned)f2b(ab[9]) << 16);
    pk.y = (unsigned)f2b(ab[10]) | ((unsigned)f2b(ab[11]) << 16);
    pk.z = (unsigned)f2b(ab[12]) | ((unsigned)f2b(ab[13]) << 16);
    pk.w = (unsigned)f2b(ab[14]) | ((unsigned)f2b(ab[15]) << 16);
    *(uint4*)((char*)xw1b + (size_t)(n0 + 1) * 32 + 16) = pk;
  } else if (j == 2) {
    *(float4*)(xr1 + (size_t)n0 * 16 + 0) =
        make_float4(aa[16], aa[17], aa[18], aa[19]);
    *(float4*)(xr1 + (size_t)n0 * 16 + 4) =
        make_float4(aa[20], aa[21], aa[22], aa[23]);
    *(float4*)(xr1 + (size_t)(n0 + 1) * 16 + 0) =
        make_float4(ab[16], ab[17], ab[18], ab[19]);
    *(float4*)(xr1 + (size_t)(n0 + 1) * 16 + 4) =
        make_float4(ab[20], ab[21], ab[22], ab[23]);
  } else {
    *(float4*)(xr1 + (size_t)n0 * 16 + 8) =
        make_float4(aa[24], aa[25], aa[26], aa[27]);
    *(float4*)(xr1 + (size_t)n0 * 16 + 12) =
        make_float4(aa[28], aa[29], aa[30], aa[31]);
    *(float4*)(xr1 + (size_t)(n0 + 1) * 16 + 8) =
        make_float4(ab[24], ab[25], ab[26], ab[27]);
    *(float4*)(xr1 + (size_t)(n0 + 1) * 16 + 12) =
        make_float4(ab[28], ab[29], ab[30], ab[31]);
  }
}

// ---------------------------------------------------------------------------
// histB: bucket histogram, LDS pre-aggregation, int4-vectorized dst reads.
// ---------------------------------------------------------------------------
__global__ __launch_bounds__(512) void histB_kernel(
    const int* __restrict__ dst, int* __restrict__ bcnt) {
  __shared__ int hc[NBUCK];
  for (int t = threadIdx.x; t < NBUCK; t += 512) hc[t] = 0;
  __syncthreads();
  int e0 = blockIdx.x * 4096 + threadIdx.x * 8;
  if (e0 + 8 <= NEDGE) {
    int4 a = *(const int4*)(dst + e0);
    int4 b = *(const int4*)(dst + e0 + 4);
    atomicAdd(&hc[a.x >> 8], 1);
    atomicAdd(&hc[a.y >> 8], 1);
    atomicAdd(&hc[a.z >> 8], 1);
    atomicAdd(&hc[a.w >> 8], 1);
    atomicAdd(&hc[b.x >> 8], 1);
    atomicAdd(&hc[b.y >> 8], 1);
    atomicAdd(&hc[b.z >> 8], 1);
    atomicAdd(&hc[b.w >> 8], 1);
  } else {
    for (int e = e0; e < NEDGE; ++e) atomicAdd(&hc[dst[e] >> 8], 1);
  }
  __syncthreads();
  for (int t = threadIdx.x; t < NBUCK; t += 512) {
    int v = hc[t];
    if (v) atomicAdd(&bcnt[t], v);
  }
}

// ---------------------------------------------------------------------------
// scan: exclusive scan of 391 counts -> boff, gcursor; set sentinels.
// ---------------------------------------------------------------------------
__global__ __launch_bounds__(512) void scan_kernel(
    const int* __restrict__ bcnt, int* __restrict__ boff,
    int* __restrict__ gcursor, int* __restrict__ rowptr) {
  __shared__ int s[512];
  int v = (threadIdx.x < NBUCK) ? bcnt[threadIdx.x] : 0;
  s[threadIdx.x] = v;
  __syncthreads();
  for (int off = 1; off < 512; off <<= 1) {
    int t = (threadIdx.x >= off) ? s[threadIdx.x - off] : 0;
    __syncthreads();
    s[threadIdx.x] += t;
    __syncthreads();
  }
  if (threadIdx.x < NBUCK) {
    int e = s[threadIdx.x] - v;
    boff[threadIdx.x] = e;
    gcursor[threadIdx.x] = e;
  }
  if (threadIdx.x == 0) {
    boff[NBUCK] = NEDGE;
    rowptr[N_NODES] = NEDGE;
  }
}

// ---------------------------------------------------------------------------
// partA: multi-split with LDS write staging (R15, measured good).
// ---------------------------------------------------------------------------
__global__ __launch_bounds__(512) void partA_kernel(
    const int* __restrict__ src, const int* __restrict__ dst,
    int* __restrict__ gcursor, unsigned* __restrict__ recs) {
  __shared__ int cnt[NBUCK];
  __shared__ int start[NBUCK];
  __shared__ int base[NBUCK];
  __shared__ int scn[512];
  __shared__ unsigned srec[4096];        // 16KB staged recs
  __shared__ unsigned short sbk[4096];   // 8KB bucket id per staged pos

  int tid = threadIdx.x;
  for (int t = tid; t < NBUCK; t += 512) cnt[t] = 0;
  __syncthreads();

  int ebase = blockIdx.x * 4096;
  int nblk = NEDGE - ebase;
  if (nblk > 4096) nblk = 4096;

  unsigned recv[8];
  int bk[8];
  int rank[8];
  int e0 = ebase + tid * 8;
  if (e0 + 8 <= NEDGE) {
    int4 d0 = *(const int4*)(dst + e0);
    int4 d1 = *(const int4*)(dst + e0 + 4);
    int4 s0 = *(const int4*)(src + e0);
    int4 s1 = *(const int4*)(src + e0 + 4);
    int dv[8] = {d0.x, d0.y, d0.z, d0.w, d1.x, d1.y, d1.z, d1.w};
    int sv[8] = {s0.x, s0.y, s0.z, s0.w, s1.x, s1.y, s1.z, s1.w};
#pragma unroll
    for (int k = 0; k < 8; ++k) {
      bk[k] = dv[k] >> 8;
      recv[k] = (unsigned)sv[k] | ((unsigned)(dv[k] & 255) << 17);
      rank[k] = atomicAdd(&cnt[bk[k]], 1);
    }
  } else {
#pragma unroll
    for (int k = 0; k < 8; ++k) {
      int e = e0 + k;
      if (e < NEDGE) {
        int d = dst[e];
        bk[k] = d >> 8;
        recv[k] = (unsigned)src[e] | ((unsigned)(d & 255) << 17);
        rank[k] = atomicAdd(&cnt[bk[k]], 1);
      } else {
        bk[k] = -1;
      }
    }
  }
  __syncthreads();

  // block exclusive scan of cnt -> start; reserve global base per bucket
  int v = (tid < NBUCK) ? cnt[tid] : 0;
  scn[tid] = v;
  __syncthreads();
  for (int off = 1; off < 512; off <<= 1) {
    int t = (tid >= off) ? scn[tid - off] : 0;
    __syncthreads();
    scn[tid] += t;
    __syncthreads();
  }
  if (tid < NBUCK) {
    start[tid] = scn[tid] - v;
    base[tid] = v ? atomicAdd(&gcursor[tid], v) : 0;
  }
  __syncthreads();

  // stage into bucket-sorted LDS
#pragma unroll
  for (int k = 0; k < 8; ++k) {
    if (bk[k] >= 0) {
      int pos = start[bk[k]] + rank[k];
      srec[pos] = recv[k];
      sbk[pos] = (unsigned short)bk[k];
    }
  }
  __syncthreads();

  // stream out: adjacent i -> adjacent global addr within each bucket run
  for (int i = tid; i < nblk; i += 512) {
    int b = sbk[i];
    recs[base[b] + (i - start[b])] = srec[i];
  }
}

// ---------------------------------------------------------------------------
// sortB: per-bucket counting sort with LDS staged output (R15, measured good).
// ---------------------------------------------------------------------------
__global__ __launch_bounds__(1024) void sortB_kernel(
    const int* __restrict__ boff, const unsigned* __restrict__ recs,
    int* __restrict__ rowptr, int* __restrict__ colsrc) {
  __shared__ int hist[256];
  __shared__ int s[256];
  __shared__ int cur[256];
  __shared__ int staged[SCAP];  // 48KB
  if (threadIdx.x < 256) hist[threadIdx.x] = 0;
  __syncthreads();

  int b = blockIdx.x;
  int beg = boff[b], end = boff[b + 1];
  for (int j = beg + threadIdx.x; j < end; j += 1024)
    atomicAdd(&hist[recs[j] >> 17], 1);
  __syncthreads();

  if (threadIdx.x < 256) s[threadIdx.x] = hist[threadIdx.x];
  __syncthreads();
  for (int off = 1; off < 256; off <<= 1) {
    int t = 0;
    if (threadIdx.x < 256 && threadIdx.x >= off) t = s[threadIdx.x - off];
    __syncthreads();
    if (threadIdx.x < 256) s[threadIdx.x] += t;
    __syncthreads();
  }
  if (threadIdx.x < 256) {
    int excl = s[threadIdx.x] - hist[threadIdx.x];
    int n = b * 256 + threadIdx.x;
    if (n < N_NODES) rowptr[n] = beg + excl;
    cur[threadIdx.x] = excl;
  }
  __syncthreads();

  for (int j = beg + threadIdx.x; j < end; j += 1024) {
    unsigned r = recs[j];
    int dl = r >> 17;
    int pos = atomicAdd(&cur[dl], 1);
    if (pos < SCAP) staged[pos] = (int)(r & 0x1FFFF);
    else colsrc[beg + pos] = (int)(r & 0x1FFFF);  // overflow fallback (rare)
  }
  __syncthreads();

  int size = end - beg;
  if (size > SCAP) size = SCAP;
  for (int i = threadIdx.x; i < size; i += 1024) colsrc[beg + i] = staged[i];
}

// ---------------------------------------------------------------------------
// gather1: 8 lanes/node; lane bit0 = d (8-dim half, 16B request),
// bits1-2 = p (4-way edge interleave). fp32 accum; fused
// mean+xr1+b1+ELU -> h (fp32) and hb (bf16 table). (unchanged)
// ---------------------------------------------------------------------------
__global__ __launch_bounds__(256) void gather1_kernel(
    const int* __restrict__ rowptr, const int* __restrict__ colsrc,
    const uint4* __restrict__ valb8, const float4* __restrict__ xr14,
    const float* __restrict__ b1, float4* __restrict__ h4,
    uint4* __restrict__ hb8) {
  int t = blockIdx.x * 256 + threadIdx.x;
  int n = t >> 3;
  if (n >= N_NODES) return;
  int d = t & 1;
  int p = (t >> 1) & 3;
  int beg = rowptr[n], end = rowptr[n + 1];

  float a[8] = {0.f, 0.f, 0.f, 0.f, 0.f, 0.f, 0.f, 0.f};
  int bA = (beg + 3) & ~3;
  int eA = end & ~3;
  if (bA > eA) {
    if (p == 0)
      for (int j = beg; j < end; ++j) accum8(valb8[colsrc[j] * 2 + d], a);
  } else {
    if (p == 0) {
      for (int j = beg; j < bA; ++j) accum8(valb8[colsrc[j] * 2 + d], a);
    } else if (p == 3) {
      for (int j = eA; j < end; ++j) accum8(valb8[colsrc[j] * 2 + d], a);
    }
    float a1[8] = {0.f, 0.f, 0.f, 0.f, 0.f, 0.f, 0.f, 0.f};
    int j = bA + p * 4;
    for (; j + 20 <= eA; j += 32) {
      v4i c0 = __builtin_nontemporal_load((const v4i*)(colsrc + j));
      v4i c1 = __builtin_nontemporal_load((const v4i*)(colsrc + j + 16));
      uint4 w0 = valb8[c0.x * 2 + d];
      uint4 w1 = valb8[c0.y * 2 + d];
      uint4 w2 = valb8[c0.z * 2 + d];
      uint4 w3 = valb8[c0.w * 2 + d];
      uint4 w4 = valb8[c1.x * 2 + d];
      uint4 w5 = valb8[c1.y * 2 + d];
      uint4 w6 = valb8[c1.z * 2 + d];
      uint4 w7 = valb8[c1.w * 2 + d];
      accum8(w0, a);
      accum8(w1, a1);
      accum8(w2, a);
      accum8(w3, a1);
      accum8(w4, a);
      accum8(w5, a1);
      accum8(w6, a);
      accum8(w7, a1);
    }
    for (; j + 4 <= eA; j += 16) {
      v4i c0 = __builtin_nontemporal_load((const v4i*)(colsrc + j));
      accum8(valb8[c0.x * 2 + d], a);
      accum8(valb8[c0.y * 2 + d], a1);
      accum8(valb8[c0.z * 2 + d], a);
      accum8(valb8[c0.w * 2 + d], a1);
    }
#pragma unroll
    for (int k = 0; k < 8; ++k) a[k] += a1[k];
  }

#pragma unroll
  for (int k = 0; k < 8; ++k) {
    a[k] += __shfl_xor(a[k], 2);
    a[k] += __shfl_xor(a[k], 4);
  }
  if (p) return;

  float inv = 1.0f / fmaxf((float)(end - beg), 1.0f);
  float4 r0 = xr14[n * 4 + 2 * d];
  float4 r1 = xr14[n * 4 + 2 * d + 1];
  const float4* bb = (const float4*)b1;
  float4 bb0 = bb[2 * d], bb1 = bb[2 * d + 1];
  float o[8];
  o[0] = a[0] * inv + r0.x + bb0.x;
  o[1] = a[1] * inv + r0.y + bb0.y;
  o[2] = a[2] * inv + r0.z + bb0.z;
  o[3] = a[3] * inv + r0.w + bb0.w;
  o[4] = a[4] * inv + r1.x + bb1.x;
  o[5] = a[5] * inv + r1.y + bb1.y;
  o[6] = a[6] * inv + r1.z + bb1.z;
  o[7] = a[7] * inv + r1.w + bb1.w;
#pragma unroll
  for (int k = 0; k < 8; ++k) o[k] = (o[k] > 0.f) ? o[k] : expm1f(o[k]);
  h4[n * 4 + 2 * d] = make_float4(o[0], o[1], o[2], o[3]);
  h4[n * 4 + 2 * d + 1] = make_float4(o[4], o[5], o[6], o[7]);
  uint4 pk;
  pk.x = (unsigned)f2b(o[0]) | ((unsigned)f2b(o[1]) << 16);
  pk.y = (unsigned)f2b(o[2]) | ((unsigned)f2b(o[3]) << 16);
  pk.z = (unsigned)f2b(o[4]) | ((unsigned)f2b(o[5]) << 16);
  pk.w = (unsigned)f2b(o[6]) | ((unsigned)f2b(o[7]) << 16);
  hb8[n * 2 + d] = pk;
}

// ---------------------------------------------------------------------------
// gather2: same structure over hb; writes mean agg2n (fp32). (unchanged)
// ---------------------------------------------------------------------------
__global__ __launch_bounds__(256) void gather2_kernel(
    const int* __restrict__ rowptr, const int* __restrict__ colsrc,
    const uint4* __restrict__ valb8, float4* __restrict__ agg2n4) {
  int t = blockIdx.x * 256 + threadIdx.x;
  int n = t >> 3;
  if (n >= N_NODES) return;
  int d = t & 1;
  int p = (t >> 1) & 3;
  int beg = rowptr[n], end = rowptr[n + 1];

  float a[8] = {0.f, 0.f, 0.f, 0.f, 0.f, 0.f, 0.f, 0.f};
  int bA = (beg + 3) & ~3;
  int eA = end & ~3;
  if (bA > eA) {
    if (p == 0)
      for (int j = beg; j < end; ++j) accum8(valb8[colsrc[j] * 2 + d], a);
  } else {
    if (p == 0) {
      for (int j = beg; j < bA; ++j) accum8(valb8[colsrc[j] * 2 + d], a);
    } else if (p == 3) {
      for (int j = eA; j < end; ++j) accum8(valb8[colsrc[j] * 2 + d], a);
    }
    float a1[8] = {0.f, 0.f, 0.f, 0.f, 0.f, 0.f, 0.f, 0.f};
    int j = bA + p * 4;
    for (; j + 20 <= eA; j += 32) {
      v4i c0 = __builtin_nontemporal_load((const v4i*)(colsrc + j));
      v4i c1 = __builtin_nontemporal_load((const v4i*)(colsrc + j + 16));
      uint4 w0 = valb8[c0.x * 2 + d];
      uint4 w1 = valb8[c0.y * 2 + d];
      uint4 w2 = valb8[c0.z * 2 + d];
      uint4 w3 = valb8[c0.w * 2 + d];
      uint4 w4 = valb8[c1.x * 2 + d];
      uint4 w5 = valb8[c1.y * 2 + d];
      uint4 w6 = valb8[c1.z * 2 + d];
      uint4 w7 = valb8[c1.w * 2 + d];
      accum8(w0, a);
      accum8(w1, a1);
      accum8(w2, a);
      accum8(w3, a1);
      accum8(w4, a);
      accum8(w5, a1);
      accum8(w6, a);
      accum8(w7, a1);
    }
    for (; j + 4 <= eA; j += 16) {
      v4i c0 = __builtin_nontemporal_load((const v4i*)(colsrc + j));
      accum8(valb8[c0.x * 2 + d], a);
      accum8(valb8[c0.y * 2 + d], a1);
      accum8(valb8[c0.z * 2 + d], a);
      accum8(valb8[c0.w * 2 + d], a1);
    }
#pragma unroll
    for (int k = 0; k < 8; ++k) a[k] += a1[k];
  }

#pragma unroll
  for (int k = 0; k < 8; ++k) {
    a[k] += __shfl_xor(a[k], 2);
    a[k] += __shfl_xor(a[k], 4);
  }
  if (p) return;

  float inv = 1.0f / fmaxf((float)(end - beg), 1.0f);
  agg2n4[n * 4 + 2 * d] =
      make_float4(a[0] * inv, a[1] * inv, a[2] * inv, a[3] * inv);
  agg2n4[n * 4 + 2 * d + 1] =
      make_float4(a[4] * inv, a[5] * inv, a[6] * inv, a[7] * inv);
}

// ---------------------------------------------------------------------------
// out: agg2n @ W2[1] + h @ root2 + b2, log_softmax, fp32 store. (unchanged)
// ---------------------------------------------------------------------------
__global__ __launch_bounds__(256) void out_kernel(
    const float* __restrict__ h, const float* __restrict__ agg2n,
    const float* __restrict__ W2, const float* __restrict__ root2,
    const float* __restrict__ b2v, float* __restrict__ out) {
  __shared__ float Wl[HID * NCLS];
  __shared__ float Rl[HID * NCLS];
  __shared__ float Bl[NCLS];
  for (int i = threadIdx.x; i < HID * NCLS; i += blockDim.x) {
    Wl[i] = W2[HID * NCLS + i];
    Rl[i] = root2[i];
  }
  if (threadIdx.x < NCLS) Bl[threadIdx.x] = b2v[threadIdx.x];
  __syncthreads();

  int n = blockIdx.x * blockDim.x + threadIdx.x;
  if (n >= N_NODES) return;

  float hv[HID], av[HID];
#pragma unroll
  for (int c = 0; c < HID; ++c) {
    hv[c] = h[n * HID + c];
    av[c] = agg2n[n * HID + c];
  }
  float logit[NCLS];
#pragma unroll
  for (int j = 0; j < NCLS; ++j) logit[j] = Bl[j];
  for (int c = 0; c < HID; ++c) {
    float hc = hv[c], ac = av[c];
#pragma unroll
    for (int j = 0; j < NCLS; ++j)
      logit[j] += ac * Wl[c * NCLS + j] + hc * Rl[c * NCLS + j];
  }
  float m = -INFINITY;
#pragma unroll
  for (int j = 0; j < NCLS; ++j) m = fmaxf(m, logit[j]);
  float s = 0.f;
#pragma unroll
  for (int j = 0; j < NCLS; ++j) s += expf(logit[j] - m);
  float lse = m + logf(s);
#pragma unroll
  for (int j = 0; j < NCLS; ++j)
    out[(size_t)n * NCLS + j] = logit[j] - lse;
}

extern "C" void kernel_launch(void* const* d_in, const int* in_sizes, int n_in,
                              void* d_out, int out_size, void* d_ws,
                              size_t ws_size, hipStream_t stream) {
  const float* x = (const float*)d_in[0];
  const int* ei = (const int*)d_in[1];  // (2, E): src row then dst row
  const float* W1 = (const float*)d_in[2];
  const float* root1 = (const float*)d_in[3];
  const float* b1 = (const float*)d_in[4];
  const float* W2 = (const float*)d_in[5];
  const float* root2 = (const float*)d_in[6];
  const float* b2v = (const float*)d_in[7];
  float* out = (float*)d_out;

  const int* src = ei;
  const int* dstp = ei + NEDGE;

  // workspace (bytes):
  // [bcnt 2K][boff 2K][gcursor 2K][rowptr (N+4)*4]
  // [recs E*4  (lower half reused as h fp32, upper half as agg2n fp32)]
  // [colsrc E*4][xw1b 16N*2][xr1 16N*4][hb 16N*2]
  char* w = (char*)d_ws;
  int* bcnt = (int*)w;           w += 2048;
  int* boff = (int*)w;           w += 2048;
  int* gcursor = (int*)w;        w += 2048;
  int* rowptr = (int*)w;         w += (size_t)(N_NODES + 4) * 4;
  unsigned* recs = (unsigned*)w; w += (size_t)NEDGE * 4;
  int* colsrc = (int*)w;         w += (size_t)NEDGE * 4;
  unsigned* xw1b = (unsigned*)w; w += (size_t)N_NODES * HID * 2;
  float* xr1 = (float*)w;        w += (size_t)N_NODES * HID * 4;
  unsigned short* hb = (unsigned short*)w; w += (size_t)N_NODES * HID * 2;

  float* h = (float*)recs;  // recs dead after sortB; h = 6.4MB (half of recs)
  float* agg2n = (float*)((char*)recs + (size_t)N_NODES * HID * 4);

  hipMemsetAsync(bcnt, 0, 2048, stream);

  proj1_kernel<<<(N_NODES + 127) / 128, 256, 0, stream>>>(x, W1, root1, xw1b,
                                                          xr1);
  histB_kernel<<<NCHUNK, 512, 0, stream>>>(dstp, bcnt);
  scan_kernel<<<1, 512, 0, stream>>>(bcnt, boff, gcursor, rowptr);
  partA_kernel<<<NCHUNK, 512, 0, stream>>>(src, dstp, gcursor, recs);
  sortB_kernel<<<NBUCK, 1024, 0, stream>>>(boff, recs, rowptr, colsrc);
  gather1_kernel<<<(N_NODES * 8 + 255) / 256, 256, 0, stream>>>(
      rowptr, colsrc, (const uint4*)xw1b, (const float4*)xr1, b1, (float4*)h,
      (uint4*)hb);
  gather2_kernel<<<(N_NODES * 8 + 255) / 256, 256, 0, stream>>>(
      rowptr, colsrc, (const uint4*)hb, (float4*)agg2n);
  out_kernel<<<(N_NODES + 255) / 256, 256, 0, stream>>>(h, agg2n, W2, root2,
                                                        b2v, out);
}

// Round 10
// 257.248 us; speedup vs baseline: 1.0641x; 1.0641x over previous
//
#include <hip/hip_runtime.h>
#include <hip/hip_bf16.h>

#define N_NODES 100000
#define FIN 128
#define HID 16
#define NCLS 40
#define NEDGE 3200000
#define NBUCK 391     // ceil(100000/256): 256 dst-nodes per bucket
#define NCHUNK 782    // ceil(NEDGE/4096)
#define SCAP 12288    // sortB staged capacity (48KB); max bucket ~8.5K

typedef int v4i __attribute__((ext_vector_type(4)));
typedef __attribute__((ext_vector_type(8))) short bf16x8;
typedef __attribute__((ext_vector_type(4))) float f32x4;

// f32 -> bf16 (RNE)
__device__ __forceinline__ unsigned short f2b(float f) {
  union { float f; unsigned u; } v;
  v.f = f;
  unsigned r = v.u + 0x7FFFu + ((v.u >> 16) & 1u);
  return (unsigned short)(r >> 16);
}

// accumulate 8 bf16 (one uint4 = 16B) into 8 fp32
__device__ __forceinline__ void accum8(uint4 w, float* a) {
  union { unsigned u; float f; } t;
  t.u = w.x << 16;         a[0] += t.f;
  t.u = w.x & 0xFFFF0000u; a[1] += t.f;
  t.u = w.y << 16;         a[2] += t.f;
  t.u = w.y & 0xFFFF0000u; a[3] += t.f;
  t.u = w.z << 16;         a[4] += t.f;
  t.u = w.z & 0xFFFF0000u; a[5] += t.f;
  t.u = w.w << 16;         a[6] += t.f;
  t.u = w.w & 0xFFFF0000u; a[7] += t.f;
}

// ---------------------------------------------------------------------------
// R17 proj1: MFMA. (100000x128)@(128x32) on the matrix pipe.
// Per wave: 16-node tile, K=128 = 4x mfma_f32_16x16x32_bf16 per 16-col group;
// group 0 = W1[1] -> xw1b (bf16), group 1 = root1 -> xr1 (fp32 from C-frag).
// W pre-converted to bf16 in LDS laid out so each lane's B-frag is one
// contiguous ds_read_b128. A-frag: lane = (g=l>>4, row=l&15), k = kb*32+g*8+i
// (k-position mapping cancels since A and B use the same placement).
// C/D: col=lane&15, row=(lane>>4)*4+reg  [m89-verified].
// ---------------------------------------------------------------------------
__global__ __launch_bounds__(256) void proj1_kernel(
    const float* __restrict__ x, const float* __restrict__ W1,
    const float* __restrict__ root1,
    unsigned* __restrict__ xw1b, float* __restrict__ xr1) {
  __shared__ unsigned short Wb[2][4][4][16][8];  // [cg][kb][g][c][i], 8KB

  int tid = threadIdx.x;
  for (int t = tid; t < 4096; t += 256) {
    int cg = t >> 11;
    int rem = t & 2047;
    int kb = rem >> 9;
    int g = (rem >> 7) & 3;
    int c = (rem >> 3) & 15;
    int i = rem & 7;
    int k = kb * 32 + g * 8 + i;
    float v = (cg == 0) ? W1[FIN * HID + k * HID + c] : root1[k * HID + c];
    Wb[cg][kb][g][c][i] = f2b(v);
  }
  __syncthreads();

  int wid = tid >> 6;
  int lane = tid & 63;
  int n0 = blockIdx.x * 64 + wid * 16;
  if (n0 >= N_NODES) return;  // wave-uniform; N % 16 == 0 covers exactly

  int row = lane & 15;
  int g = lane >> 4;
  const float* xp = x + (size_t)(n0 + row) * FIN + g * 8;

  bf16x8 afr[4];
#pragma unroll
  for (int kb = 0; kb < 4; ++kb) {
    float4 u0 = *(const float4*)(xp + kb * 32);
    float4 u1 = *(const float4*)(xp + kb * 32 + 4);
    bf16x8 a;
    a[0] = (short)f2b(u0.x);
    a[1] = (short)f2b(u0.y);
    a[2] = (short)f2b(u0.z);
    a[3] = (short)f2b(u0.w);
    a[4] = (short)f2b(u1.x);
    a[5] = (short)f2b(u1.y);
    a[6] = (short)f2b(u1.z);
    a[7] = (short)f2b(u1.w);
    afr[kb] = a;
  }

  f32x4 c0 = {0.f, 0.f, 0.f, 0.f};
  f32x4 c1 = {0.f, 0.f, 0.f, 0.f};
#pragma unroll
  for (int kb = 0; kb < 4; ++kb) {
    bf16x8 b0 = *(const bf16x8*)&Wb[0][kb][g][row][0];
    c0 = __builtin_amdgcn_mfma_f32_16x16x32_bf16(afr[kb], b0, c0, 0, 0, 0);
  }
#pragma unroll
  for (int kb = 0; kb < 4; ++kb) {
    bf16x8 b1 = *(const bf16x8*)&Wb[1][kb][g][row][0];
    c1 = __builtin_amdgcn_mfma_f32_16x16x32_bf16(afr[kb], b1, c1, 0, 0, 0);
  }

  // store: this lane holds output col = lane&15, rows g*4 + r
  int col = lane & 15;
  unsigned short* xwu = (unsigned short*)xw1b;
#pragma unroll
  for (int r = 0; r < 4; ++r) {
    int n = n0 + g * 4 + r;
    xwu[(size_t)n * HID + col] = f2b(c1[r] * 0.f + c0[r]);
    xr1[(size_t)n * HID + col] = c1[r];
  }
}

// ---------------------------------------------------------------------------
// histB: bucket histogram, LDS pre-aggregation, int4-vectorized dst reads.
// ---------------------------------------------------------------------------
__global__ __launch_bounds__(512) void histB_kernel(
    const int* __restrict__ dst, int* __restrict__ bcnt) {
  __shared__ int hc[NBUCK];
  for (int t = threadIdx.x; t < NBUCK; t += 512) hc[t] = 0;
  __syncthreads();
  int e0 = blockIdx.x * 4096 + threadIdx.x * 8;
  if (e0 + 8 <= NEDGE) {
    int4 a = *(const int4*)(dst + e0);
    int4 b = *(const int4*)(dst + e0 + 4);
    atomicAdd(&hc[a.x >> 8], 1);
    atomicAdd(&hc[a.y >> 8], 1);
    atomicAdd(&hc[a.z >> 8], 1);
    atomicAdd(&hc[a.w >> 8], 1);
    atomicAdd(&hc[b.x >> 8], 1);
    atomicAdd(&hc[b.y >> 8], 1);
    atomicAdd(&hc[b.z >> 8], 1);
    atomicAdd(&hc[b.w >> 8], 1);
  } else {
    for (int e = e0; e < NEDGE; ++e) atomicAdd(&hc[dst[e] >> 8], 1);
  }
  __syncthreads();
  for (int t = threadIdx.x; t < NBUCK; t += 512) {
    int v = hc[t];
    if (v) atomicAdd(&bcnt[t], v);
  }
}

// ---------------------------------------------------------------------------
// scan: exclusive scan of 391 counts -> boff, gcursor; set sentinels.
// ---------------------------------------------------------------------------
__global__ __launch_bounds__(512) void scan_kernel(
    const int* __restrict__ bcnt, int* __restrict__ boff,
    int* __restrict__ gcursor, int* __restrict__ rowptr) {
  __shared__ int s[512];
  int v = (threadIdx.x < NBUCK) ? bcnt[threadIdx.x] : 0;
  s[threadIdx.x] = v;
  __syncthreads();
  for (int off = 1; off < 512; off <<= 1) {
    int t = (threadIdx.x >= off) ? s[threadIdx.x - off] : 0;
    __syncthreads();
    s[threadIdx.x] += t;
    __syncthreads();
  }
  if (threadIdx.x < NBUCK) {
    int e = s[threadIdx.x] - v;
    boff[threadIdx.x] = e;
    gcursor[threadIdx.x] = e;
  }
  if (threadIdx.x == 0) {
    boff[NBUCK] = NEDGE;
    rowptr[N_NODES] = NEDGE;
  }
}

// ---------------------------------------------------------------------------
// partA: multi-split with LDS write staging (R15, measured good).
// ---------------------------------------------------------------------------
__global__ __launch_bounds__(512) void partA_kernel(
    const int* __restrict__ src, const int* __restrict__ dst,
    int* __restrict__ gcursor, unsigned* __restrict__ recs) {
  __shared__ int cnt[NBUCK];
  __shared__ int start[NBUCK];
  __shared__ int base[NBUCK];
  __shared__ int scn[512];
  __shared__ unsigned srec[4096];        // 16KB staged recs
  __shared__ unsigned short sbk[4096];   // 8KB bucket id per staged pos

  int tid = threadIdx.x;
  for (int t = tid; t < NBUCK; t += 512) cnt[t] = 0;
  __syncthreads();

  int ebase = blockIdx.x * 4096;
  int nblk = NEDGE - ebase;
  if (nblk > 4096) nblk = 4096;

  unsigned recv[8];
  int bk[8];
  int rank[8];
  int e0 = ebase + tid * 8;
  if (e0 + 8 <= NEDGE) {
    int4 d0 = *(const int4*)(dst + e0);
    int4 d1 = *(const int4*)(dst + e0 + 4);
    int4 s0 = *(const int4*)(src + e0);
    int4 s1 = *(const int4*)(src + e0 + 4);
    int dv[8] = {d0.x, d0.y, d0.z, d0.w, d1.x, d1.y, d1.z, d1.w};
    int sv[8] = {s0.x, s0.y, s0.z, s0.w, s1.x, s1.y, s1.z, s1.w};
#pragma unroll
    for (int k = 0; k < 8; ++k) {
      bk[k] = dv[k] >> 8;
      recv[k] = (unsigned)sv[k] | ((unsigned)(dv[k] & 255) << 17);
      rank[k] = atomicAdd(&cnt[bk[k]], 1);
    }
  } else {
#pragma unroll
    for (int k = 0; k < 8; ++k) {
      int e = e0 + k;
      if (e < NEDGE) {
        int d = dst[e];
        bk[k] = d >> 8;
        recv[k] = (unsigned)src[e] | ((unsigned)(d & 255) << 17);
        rank[k] = atomicAdd(&cnt[bk[k]], 1);
      } else {
        bk[k] = -1;
      }
    }
  }
  __syncthreads();

  int v = (tid < NBUCK) ? cnt[tid] : 0;
  scn[tid] = v;
  __syncthreads();
  for (int off = 1; off < 512; off <<= 1) {
    int t = (tid >= off) ? scn[tid - off] : 0;
    __syncthreads();
    scn[tid] += t;
    __syncthreads();
  }
  if (tid < NBUCK) {
    start[tid] = scn[tid] - v;
    base[tid] = v ? atomicAdd(&gcursor[tid], v) : 0;
  }
  __syncthreads();

#pragma unroll
  for (int k = 0; k < 8; ++k) {
    if (bk[k] >= 0) {
      int pos = start[bk[k]] + rank[k];
      srec[pos] = recv[k];
      sbk[pos] = (unsigned short)bk[k];
    }
  }
  __syncthreads();

  for (int i = tid; i < nblk; i += 512) {
    int b = sbk[i];
    recs[base[b] + (i - start[b])] = srec[i];
  }
}

// ---------------------------------------------------------------------------
// sortB: per-bucket counting sort with LDS staged output (R15, measured good).
// ---------------------------------------------------------------------------
__global__ __launch_bounds__(1024) void sortB_kernel(
    const int* __restrict__ boff, const unsigned* __restrict__ recs,
    int* __restrict__ rowptr, int* __restrict__ colsrc) {
  __shared__ int hist[256];
  __shared__ int s[256];
  __shared__ int cur[256];
  __shared__ int staged[SCAP];  // 48KB
  if (threadIdx.x < 256) hist[threadIdx.x] = 0;
  __syncthreads();

  int b = blockIdx.x;
  int beg = boff[b], end = boff[b + 1];
  for (int j = beg + threadIdx.x; j < end; j += 1024)
    atomicAdd(&hist[recs[j] >> 17], 1);
  __syncthreads();

  if (threadIdx.x < 256) s[threadIdx.x] = hist[threadIdx.x];
  __syncthreads();
  for (int off = 1; off < 256; off <<= 1) {
    int t = 0;
    if (threadIdx.x < 256 && threadIdx.x >= off) t = s[threadIdx.x - off];
    __syncthreads();
    if (threadIdx.x < 256) s[threadIdx.x] += t;
    __syncthreads();
  }
  if (threadIdx.x < 256) {
    int excl = s[threadIdx.x] - hist[threadIdx.x];
    int n = b * 256 + threadIdx.x;
    if (n < N_NODES) rowptr[n] = beg + excl;
    cur[threadIdx.x] = excl;
  }
  __syncthreads();

  for (int j = beg + threadIdx.x; j < end; j += 1024) {
    unsigned r = recs[j];
    int dl = r >> 17;
    int pos = atomicAdd(&cur[dl], 1);
    if (pos < SCAP) staged[pos] = (int)(r & 0x1FFFF);
    else colsrc[beg + pos] = (int)(r & 0x1FFFF);  // overflow fallback (rare)
  }
  __syncthreads();

  int size = end - beg;
  if (size > SCAP) size = SCAP;
  for (int i = threadIdx.x; i < size; i += 1024) colsrc[beg + i] = staged[i];
}

// ---------------------------------------------------------------------------
// gather1: 8 lanes/node; lane bit0 = d (8-dim half, 16B request),
// bits1-2 = p (4-way edge interleave). fp32 accum; fused
// mean+xr1+b1+ELU -> h (fp32) and hb (bf16 table). (unchanged)
// ---------------------------------------------------------------------------
__global__ __launch_bounds__(256) void gather1_kernel(
    const int* __restrict__ rowptr, const int* __restrict__ colsrc,
    const uint4* __restrict__ valb8, const float4* __restrict__ xr14,
    const float* __restrict__ b1, float4* __restrict__ h4,
    uint4* __restrict__ hb8) {
  int t = blockIdx.x * 256 + threadIdx.x;
  int n = t >> 3;
  if (n >= N_NODES) return;
  int d = t & 1;
  int p = (t >> 1) & 3;
  int beg = rowptr[n], end = rowptr[n + 1];

  float a[8] = {0.f, 0.f, 0.f, 0.f, 0.f, 0.f, 0.f, 0.f};
  int bA = (beg + 3) & ~3;
  int eA = end & ~3;
  if (bA > eA) {
    if (p == 0)
      for (int j = beg; j < end; ++j) accum8(valb8[colsrc[j] * 2 + d], a);
  } else {
    if (p == 0) {
      for (int j = beg; j < bA; ++j) accum8(valb8[colsrc[j] * 2 + d], a);
    } else if (p == 3) {
      for (int j = eA; j < end; ++j) accum8(valb8[colsrc[j] * 2 + d], a);
    }
    float a1[8] = {0.f, 0.f, 0.f, 0.f, 0.f, 0.f, 0.f, 0.f};
    int j = bA + p * 4;
    for (; j + 20 <= eA; j += 32) {
      v4i c0 = __builtin_nontemporal_load((const v4i*)(colsrc + j));
      v4i c1 = __builtin_nontemporal_load((const v4i*)(colsrc + j + 16));
      uint4 w0 = valb8[c0.x * 2 + d];
      uint4 w1 = valb8[c0.y * 2 + d];
      uint4 w2 = valb8[c0.z * 2 + d];
      uint4 w3 = valb8[c0.w * 2 + d];
      uint4 w4 = valb8[c1.x * 2 + d];
      uint4 w5 = valb8[c1.y * 2 + d];
      uint4 w6 = valb8[c1.z * 2 + d];
      uint4 w7 = valb8[c1.w * 2 + d];
      accum8(w0, a);
      accum8(w1, a1);
      accum8(w2, a);
      accum8(w3, a1);
      accum8(w4, a);
      accum8(w5, a1);
      accum8(w6, a);
      accum8(w7, a1);
    }
    for (; j + 4 <= eA; j += 16) {
      v4i c0 = __builtin_nontemporal_load((const v4i*)(colsrc + j));
      accum8(valb8[c0.x * 2 + d], a);
      accum8(valb8[c0.y * 2 + d], a1);
      accum8(valb8[c0.z * 2 + d], a);
      accum8(valb8[c0.w * 2 + d], a1);
    }
#pragma unroll
    for (int k = 0; k < 8; ++k) a[k] += a1[k];
  }

#pragma unroll
  for (int k = 0; k < 8; ++k) {
    a[k] += __shfl_xor(a[k], 2);
    a[k] += __shfl_xor(a[k], 4);
  }
  if (p) return;

  float inv = 1.0f / fmaxf((float)(end - beg), 1.0f);
  float4 r0 = xr14[n * 4 + 2 * d];
  float4 r1 = xr14[n * 4 + 2 * d + 1];
  const float4* bb = (const float4*)b1;
  float4 bb0 = bb[2 * d], bb1 = bb[2 * d + 1];
  float o[8];
  o[0] = a[0] * inv + r0.x + bb0.x;
  o[1] = a[1] * inv + r0.y + bb0.y;
  o[2] = a[2] * inv + r0.z + bb0.z;
  o[3] = a[3] * inv + r0.w + bb0.w;
  o[4] = a[4] * inv + r1.x + bb1.x;
  o[5] = a[5] * inv + r1.y + bb1.y;
  o[6] = a[6] * inv + r1.z + bb1.z;
  o[7] = a[7] * inv + r1.w + bb1.w;
#pragma unroll
  for (int k = 0; k < 8; ++k) o[k] = (o[k] > 0.f) ? o[k] : expm1f(o[k]);
  h4[n * 4 + 2 * d] = make_float4(o[0], o[1], o[2], o[3]);
  h4[n * 4 + 2 * d + 1] = make_float4(o[4], o[5], o[6], o[7]);
  uint4 pk;
  pk.x = (unsigned)f2b(o[0]) | ((unsigned)f2b(o[1]) << 16);
  pk.y = (unsigned)f2b(o[2]) | ((unsigned)f2b(o[3]) << 16);
  pk.z = (unsigned)f2b(o[4]) | ((unsigned)f2b(o[5]) << 16);
  pk.w = (unsigned)f2b(o[6]) | ((unsigned)f2b(o[7]) << 16);
  hb8[n * 2 + d] = pk;
}

// ---------------------------------------------------------------------------
// gather2: same structure over hb; writes mean agg2n (fp32). (unchanged)
// ---------------------------------------------------------------------------
__global__ __launch_bounds__(256) void gather2_kernel(
    const int* __restrict__ rowptr, const int* __restrict__ colsrc,
    const uint4* __restrict__ valb8, float4* __restrict__ agg2n4) {
  int t = blockIdx.x * 256 + threadIdx.x;
  int n = t >> 3;
  if (n >= N_NODES) return;
  int d = t & 1;
  int p = (t >> 1) & 3;
  int beg = rowptr[n], end = rowptr[n + 1];

  float a[8] = {0.f, 0.f, 0.f, 0.f, 0.f, 0.f, 0.f, 0.f};
  int bA = (beg + 3) & ~3;
  int eA = end & ~3;
  if (bA > eA) {
    if (p == 0)
      for (int j = beg; j < end; ++j) accum8(valb8[colsrc[j] * 2 + d], a);
  } else {
    if (p == 0) {
      for (int j = beg; j < bA; ++j) accum8(valb8[colsrc[j] * 2 + d], a);
    } else if (p == 3) {
      for (int j = eA; j < end; ++j) accum8(valb8[colsrc[j] * 2 + d], a);
    }
    float a1[8] = {0.f, 0.f, 0.f, 0.f, 0.f, 0.f, 0.f, 0.f};
    int j = bA + p * 4;
    for (; j + 20 <= eA; j += 32) {
      v4i c0 = __builtin_nontemporal_load((const v4i*)(colsrc + j));
      v4i c1 = __builtin_nontemporal_load((const v4i*)(colsrc + j + 16));
      uint4 w0 = valb8[c0.x * 2 + d];
      uint4 w1 = valb8[c0.y * 2 + d];
      uint4 w2 = valb8[c0.z * 2 + d];
      uint4 w3 = valb8[c0.w * 2 + d];
      uint4 w4 = valb8[c1.x * 2 + d];
      uint4 w5 = valb8[c1.y * 2 + d];
      uint4 w6 = valb8[c1.z * 2 + d];
      uint4 w7 = valb8[c1.w * 2 + d];
      accum8(w0, a);
      accum8(w1, a1);
      accum8(w2, a);
      accum8(w3, a1);
      accum8(w4, a);
      accum8(w5, a1);
      accum8(w6, a);
      accum8(w7, a1);
    }
    for (; j + 4 <= eA; j += 16) {
      v4i c0 = __builtin_nontemporal_load((const v4i*)(colsrc + j));
      accum8(valb8[c0.x * 2 + d], a);
      accum8(valb8[c0.y * 2 + d], a1);
      accum8(valb8[c0.z * 2 + d], a);
      accum8(valb8[c0.w * 2 + d], a1);
    }
#pragma unroll
    for (int k = 0; k < 8; ++k) a[k] += a1[k];
  }

#pragma unroll
  for (int k = 0; k < 8; ++k) {
    a[k] += __shfl_xor(a[k], 2);
    a[k] += __shfl_xor(a[k], 4);
  }
  if (p) return;

  float inv = 1.0f / fmaxf((float)(end - beg), 1.0f);
  agg2n4[n * 4 + 2 * d] =
      make_float4(a[0] * inv, a[1] * inv, a[2] * inv, a[3] * inv);
  agg2n4[n * 4 + 2 * d + 1] =
      make_float4(a[4] * inv, a[5] * inv, a[6] * inv, a[7] * inv);
}

// ---------------------------------------------------------------------------
// out: agg2n @ W2[1] + h @ root2 + b2, log_softmax, fp32 store. (unchanged)
// ---------------------------------------------------------------------------
__global__ __launch_bounds__(256) void out_kernel(
    const float* __restrict__ h, const float* __restrict__ agg2n,
    const float* __restrict__ W2, const float* __restrict__ root2,
    const float* __restrict__ b2v, float* __restrict__ out) {
  __shared__ float Wl[HID * NCLS];
  __shared__ float Rl[HID * NCLS];
  __shared__ float Bl[NCLS];
  for (int i = threadIdx.x; i < HID * NCLS; i += blockDim.x) {
    Wl[i] = W2[HID * NCLS + i];
    Rl[i] = root2[i];
  }
  if (threadIdx.x < NCLS) Bl[threadIdx.x] = b2v[threadIdx.x];
  __syncthreads();

  int n = blockIdx.x * blockDim.x + threadIdx.x;
  if (n >= N_NODES) return;

  float hv[HID], av[HID];
#pragma unroll
  for (int c = 0; c < HID; ++c) {
    hv[c] = h[n * HID + c];
    av[c] = agg2n[n * HID + c];
  }
  float logit[NCLS];
#pragma unroll
  for (int j = 0; j < NCLS; ++j) logit[j] = Bl[j];
  for (int c = 0; c < HID; ++c) {
    float hc = hv[c], ac = av[c];
#pragma unroll
    for (int j = 0; j < NCLS; ++j)
      logit[j] += ac * Wl[c * NCLS + j] + hc * Rl[c * NCLS + j];
  }
  float m = -INFINITY;
#pragma unroll
  for (int j = 0; j < NCLS; ++j) m = fmaxf(m, logit[j]);
  float s = 0.f;
#pragma unroll
  for (int j = 0; j < NCLS; ++j) s += expf(logit[j] - m);
  float lse = m + logf(s);
#pragma unroll
  for (int j = 0; j < NCLS; ++j)
    out[(size_t)n * NCLS + j] = logit[j] - lse;
}

extern "C" void kernel_launch(void* const* d_in, const int* in_sizes, int n_in,
                              void* d_out, int out_size, void* d_ws,
                              size_t ws_size, hipStream_t stream) {
  const float* x = (const float*)d_in[0];
  const int* ei = (const int*)d_in[1];  // (2, E): src row then dst row
  const float* W1 = (const float*)d_in[2];
  const float* root1 = (const float*)d_in[3];
  const float* b1 = (const float*)d_in[4];
  const float* W2 = (const float*)d_in[5];
  const float* root2 = (const float*)d_in[6];
  const float* b2v = (const float*)d_in[7];
  float* out = (float*)d_out;

  const int* src = ei;
  const int* dstp = ei + NEDGE;

  // workspace (bytes):
  // [bcnt 2K][boff 2K][gcursor 2K][rowptr (N+4)*4]
  // [recs E*4  (lower half reused as h fp32, upper half as agg2n fp32)]
  // [colsrc E*4][xw1b 16N*2][xr1 16N*4][hb 16N*2]
  char* w = (char*)d_ws;
  int* bcnt = (int*)w;           w += 2048;
  int* boff = (int*)w;           w += 2048;
  int* gcursor = (int*)w;        w += 2048;
  int* rowptr = (int*)w;         w += (size_t)(N_NODES + 4) * 4;
  unsigned* recs = (unsigned*)w; w += (size_t)NEDGE * 4;
  int* colsrc = (int*)w;         w += (size_t)NEDGE * 4;
  unsigned* xw1b = (unsigned*)w; w += (size_t)N_NODES * HID * 2;
  float* xr1 = (float*)w;        w += (size_t)N_NODES * HID * 4;
  unsigned short* hb = (unsigned short*)w; w += (size_t)N_NODES * HID * 2;

  float* h = (float*)recs;  // recs dead after sortB; h = 6.4MB (half of recs)
  float* agg2n = (float*)((char*)recs + (size_t)N_NODES * HID * 4);

  hipMemsetAsync(bcnt, 0, 2048, stream);

  proj1_kernel<<<(N_NODES + 63) / 64, 256, 0, stream>>>(x, W1, root1, xw1b,
                                                        xr1);
  histB_kernel<<<NCHUNK, 512, 0, stream>>>(dstp, bcnt);
  scan_kernel<<<1, 512, 0, stream>>>(bcnt, boff, gcursor, rowptr);
  partA_kernel<<<NCHUNK, 512, 0, stream>>>(src, dstp, gcursor, recs);
  sortB_kernel<<<NBUCK, 1024, 0, stream>>>(boff, recs, rowptr, colsrc);
  gather1_kernel<<<(N_NODES * 8 + 255) / 256, 256, 0, stream>>>(
      rowptr, colsrc, (const uint4*)xw1b, (const float4*)xr1, b1, (float4*)h,
      (uint4*)hb);
  gather2_kernel<<<(N_NODES * 8 + 255) / 256, 256, 0, stream>>>(
      rowptr, colsrc, (const uint4*)hb, (float4*)agg2n);
  out_kernel<<<(N_NODES + 255) / 256, 256, 0, stream>>>(h, agg2n, W2, root2,
                                                        b2v, out);
}

// Round 11
// 242.871 us; speedup vs baseline: 1.1271x; 1.0592x over previous
//
#include <hip/hip_runtime.h>
#include <hip/hip_bf16.h>

#define N_NODES 100000
#define FIN 128
#define HID 16
#define NCLS 40
#define NEDGE 3200000
#define NBUCK 391     // ceil(100000/256): 256 dst-nodes per bucket
#define NCHUNK 782    // ceil(NEDGE/4096)
#define PROJB 782     // ceil(100000/128): proj1 blocks in packed mid kernel
#define SCAP 12288    // sortB staged capacity (48KB); max bucket ~8.5K

typedef int v4i __attribute__((ext_vector_type(4)));
typedef __attribute__((ext_vector_type(8))) short bf16x8;
typedef __attribute__((ext_vector_type(4))) float f32x4;

// f32 -> bf16 (RNE)
__device__ __forceinline__ unsigned short f2b(float f) {
  union { float f; unsigned u; } v;
  v.f = f;
  unsigned r = v.u + 0x7FFFu + ((v.u >> 16) & 1u);
  return (unsigned short)(r >> 16);
}

// accumulate 8 bf16 (one uint4 = 16B) into 8 fp32
__device__ __forceinline__ void accum8(uint4 w, float* a) {
  union { unsigned u; float f; } t;
  t.u = w.x << 16;         a[0] += t.f;
  t.u = w.x & 0xFFFF0000u; a[1] += t.f;
  t.u = w.y << 16;         a[2] += t.f;
  t.u = w.y & 0xFFFF0000u; a[3] += t.f;
  t.u = w.z << 16;         a[4] += t.f;
  t.u = w.z & 0xFFFF0000u; a[5] += t.f;
  t.u = w.w << 16;         a[6] += t.f;
  t.u = w.w & 0xFFFF0000u; a[7] += t.f;
}

// ---------------------------------------------------------------------------
// histB: bucket histogram, LDS pre-aggregation, int4-vectorized dst reads.
// ---------------------------------------------------------------------------
__global__ __launch_bounds__(512) void histB_kernel(
    const int* __restrict__ dst, int* __restrict__ bcnt) {
  __shared__ int hc[NBUCK];
  for (int t = threadIdx.x; t < NBUCK; t += 512) hc[t] = 0;
  __syncthreads();
  int e0 = blockIdx.x * 4096 + threadIdx.x * 8;
  if (e0 + 8 <= NEDGE) {
    int4 a = *(const int4*)(dst + e0);
    int4 b = *(const int4*)(dst + e0 + 4);
    atomicAdd(&hc[a.x >> 8], 1);
    atomicAdd(&hc[a.y >> 8], 1);
    atomicAdd(&hc[a.z >> 8], 1);
    atomicAdd(&hc[a.w >> 8], 1);
    atomicAdd(&hc[b.x >> 8], 1);
    atomicAdd(&hc[b.y >> 8], 1);
    atomicAdd(&hc[b.z >> 8], 1);
    atomicAdd(&hc[b.w >> 8], 1);
  } else {
    for (int e = e0; e < NEDGE; ++e) atomicAdd(&hc[dst[e] >> 8], 1);
  }
  __syncthreads();
  for (int t = threadIdx.x; t < NBUCK; t += 512) {
    int v = hc[t];
    if (v) atomicAdd(&bcnt[t], v);
  }
}

// ---------------------------------------------------------------------------
// scan: exclusive scan of 391 counts -> boff, gcursor; set sentinels.
// ---------------------------------------------------------------------------
__global__ __launch_bounds__(512) void scan_kernel(
    const int* __restrict__ bcnt, int* __restrict__ boff,
    int* __restrict__ gcursor, int* __restrict__ rowptr) {
  __shared__ int s[512];
  int v = (threadIdx.x < NBUCK) ? bcnt[threadIdx.x] : 0;
  s[threadIdx.x] = v;
  __syncthreads();
  for (int off = 1; off < 512; off <<= 1) {
    int t = (threadIdx.x >= off) ? s[threadIdx.x - off] : 0;
    __syncthreads();
    s[threadIdx.x] += t;
    __syncthreads();
  }
  if (threadIdx.x < NBUCK) {
    int e = s[threadIdx.x] - v;
    boff[threadIdx.x] = e;
    gcursor[threadIdx.x] = e;
  }
  if (threadIdx.x == 0) {
    boff[NBUCK] = NEDGE;
    rowptr[N_NODES] = NEDGE;
  }
}

// ---------------------------------------------------------------------------
// R18 mid: PACKED partA || proj1 in one kernel (independent work; partA is
// latency-bound VALUBusy~3%, proj1 is MFMA-heavy -> complementary pipes,
// co-resident on CUs instead of serialized on the stream).
// blocks [0,NCHUNK): partA (R15 LDS write-staging, measured good).
// blocks [NCHUNK,NCHUNK+PROJB): proj1 MFMA (R17, measured good) at 8 waves
// = 128 nodes/block. LDS is a 31KB union (partA layout | proj1 Wb 8KB).
// ---------------------------------------------------------------------------
__global__ __launch_bounds__(512) void mid_kernel(
    const int* __restrict__ src, const int* __restrict__ dst,
    int* __restrict__ gcursor, unsigned* __restrict__ recs,
    const float* __restrict__ x, const float* __restrict__ W1,
    const float* __restrict__ root1,
    unsigned* __restrict__ xw1b, float* __restrict__ xr1) {
  __shared__ __attribute__((aligned(16))) char smem[31328];
  int tid = threadIdx.x;

  if (blockIdx.x < NCHUNK) {
    // ---- partA ----
    int* cnt = (int*)smem;                          // 391 ints
    int* start = (int*)(smem + 1568);               // 391 ints
    int* base = (int*)(smem + 3136);                // 391 ints
    int* scn = (int*)(smem + 4704);                 // 512 ints
    unsigned* srec = (unsigned*)(smem + 6752);      // 4096 u32
    unsigned short* sbk = (unsigned short*)(smem + 23136);  // 4096 u16

    for (int t = tid; t < NBUCK; t += 512) cnt[t] = 0;
    __syncthreads();

    int ebase = blockIdx.x * 4096;
    int nblk = NEDGE - ebase;
    if (nblk > 4096) nblk = 4096;

    unsigned recv[8];
    int bk[8];
    int rank[8];
    int e0 = ebase + tid * 8;
    if (e0 + 8 <= NEDGE) {
      int4 d0 = *(const int4*)(dst + e0);
      int4 d1 = *(const int4*)(dst + e0 + 4);
      int4 s0 = *(const int4*)(src + e0);
      int4 s1 = *(const int4*)(src + e0 + 4);
      int dv[8] = {d0.x, d0.y, d0.z, d0.w, d1.x, d1.y, d1.z, d1.w};
      int sv[8] = {s0.x, s0.y, s0.z, s0.w, s1.x, s1.y, s1.z, s1.w};
#pragma unroll
      for (int k = 0; k < 8; ++k) {
        bk[k] = dv[k] >> 8;
        recv[k] = (unsigned)sv[k] | ((unsigned)(dv[k] & 255) << 17);
        rank[k] = atomicAdd(&cnt[bk[k]], 1);
      }
    } else {
#pragma unroll
      for (int k = 0; k < 8; ++k) {
        int e = e0 + k;
        if (e < NEDGE) {
          int d = dst[e];
          bk[k] = d >> 8;
          recv[k] = (unsigned)src[e] | ((unsigned)(d & 255) << 17);
          rank[k] = atomicAdd(&cnt[bk[k]], 1);
        } else {
          bk[k] = -1;
        }
      }
    }
    __syncthreads();

    int v = (tid < NBUCK) ? cnt[tid] : 0;
    scn[tid] = v;
    __syncthreads();
    for (int off = 1; off < 512; off <<= 1) {
      int t = (tid >= off) ? scn[tid - off] : 0;
      __syncthreads();
      scn[tid] += t;
      __syncthreads();
    }
    if (tid < NBUCK) {
      start[tid] = scn[tid] - v;
      base[tid] = v ? atomicAdd(&gcursor[tid], v) : 0;
    }
    __syncthreads();

#pragma unroll
    for (int k = 0; k < 8; ++k) {
      if (bk[k] >= 0) {
        int pos = start[bk[k]] + rank[k];
        srec[pos] = recv[k];
        sbk[pos] = (unsigned short)bk[k];
      }
    }
    __syncthreads();

    for (int i = tid; i < nblk; i += 512) {
      int b = sbk[i];
      recs[base[b] + (i - start[b])] = srec[i];
    }
  } else {
    // ---- proj1 (MFMA) ----
    unsigned short* Wb = (unsigned short*)smem;  // [2][4][4][16][8]
    for (int t = tid; t < 4096; t += 512) {
      int cg = t >> 11;
      int rem = t & 2047;
      int kb = rem >> 9;
      int g = (rem >> 7) & 3;
      int c = (rem >> 3) & 15;
      int i = rem & 7;
      int k = kb * 32 + g * 8 + i;
      float v = (cg == 0) ? W1[FIN * HID + k * HID + c] : root1[k * HID + c];
      Wb[((((cg * 4 + kb) * 4 + g) * 16) + c) * 8 + i] = f2b(v);
    }
    __syncthreads();

    int wid = tid >> 6;
    int lane = tid & 63;
    int n0 = (blockIdx.x - NCHUNK) * 128 + wid * 16;
    if (n0 >= N_NODES) return;  // wave-uniform

    int row = lane & 15;
    int g = lane >> 4;
    const float* xp = x + (size_t)(n0 + row) * FIN + g * 8;

    bf16x8 afr[4];
#pragma unroll
    for (int kb = 0; kb < 4; ++kb) {
      float4 u0 = *(const float4*)(xp + kb * 32);
      float4 u1 = *(const float4*)(xp + kb * 32 + 4);
      bf16x8 a;
      a[0] = (short)f2b(u0.x);
      a[1] = (short)f2b(u0.y);
      a[2] = (short)f2b(u0.z);
      a[3] = (short)f2b(u0.w);
      a[4] = (short)f2b(u1.x);
      a[5] = (short)f2b(u1.y);
      a[6] = (short)f2b(u1.z);
      a[7] = (short)f2b(u1.w);
      afr[kb] = a;
    }

    f32x4 c0 = {0.f, 0.f, 0.f, 0.f};
    f32x4 c1 = {0.f, 0.f, 0.f, 0.f};
#pragma unroll
    for (int kb = 0; kb < 4; ++kb) {
      bf16x8 b0 = *(const bf16x8*)&Wb[(((0 * 4 + kb) * 4 + g) * 16 + row) * 8];
      c0 = __builtin_amdgcn_mfma_f32_16x16x32_bf16(afr[kb], b0, c0, 0, 0, 0);
    }
#pragma unroll
    for (int kb = 0; kb < 4; ++kb) {
      bf16x8 b1 = *(const bf16x8*)&Wb[(((1 * 4 + kb) * 4 + g) * 16 + row) * 8];
      c1 = __builtin_amdgcn_mfma_f32_16x16x32_bf16(afr[kb], b1, c1, 0, 0, 0);
    }

    int col = lane & 15;
    unsigned short* xwu = (unsigned short*)xw1b;
#pragma unroll
    for (int r = 0; r < 4; ++r) {
      int n = n0 + g * 4 + r;
      xwu[(size_t)n * HID + col] = f2b(c0[r]);
      xr1[(size_t)n * HID + col] = c1[r];
    }
  }
}

// ---------------------------------------------------------------------------
// sortB: per-bucket counting sort with LDS staged output (R15, measured good).
// ---------------------------------------------------------------------------
__global__ __launch_bounds__(1024) void sortB_kernel(
    const int* __restrict__ boff, const unsigned* __restrict__ recs,
    int* __restrict__ rowptr, int* __restrict__ colsrc) {
  __shared__ int hist[256];
  __shared__ int s[256];
  __shared__ int cur[256];
  __shared__ int staged[SCAP];  // 48KB
  if (threadIdx.x < 256) hist[threadIdx.x] = 0;
  __syncthreads();

  int b = blockIdx.x;
  int beg = boff[b], end = boff[b + 1];
  for (int j = beg + threadIdx.x; j < end; j += 1024)
    atomicAdd(&hist[recs[j] >> 17], 1);
  __syncthreads();

  if (threadIdx.x < 256) s[threadIdx.x] = hist[threadIdx.x];
  __syncthreads();
  for (int off = 1; off < 256; off <<= 1) {
    int t = 0;
    if (threadIdx.x < 256 && threadIdx.x >= off) t = s[threadIdx.x - off];
    __syncthreads();
    if (threadIdx.x < 256) s[threadIdx.x] += t;
    __syncthreads();
  }
  if (threadIdx.x < 256) {
    int excl = s[threadIdx.x] - hist[threadIdx.x];
    int n = b * 256 + threadIdx.x;
    if (n < N_NODES) rowptr[n] = beg + excl;
    cur[threadIdx.x] = excl;
  }
  __syncthreads();

  for (int j = beg + threadIdx.x; j < end; j += 1024) {
    unsigned r = recs[j];
    int dl = r >> 17;
    int pos = atomicAdd(&cur[dl], 1);
    if (pos < SCAP) staged[pos] = (int)(r & 0x1FFFF);
    else colsrc[beg + pos] = (int)(r & 0x1FFFF);  // overflow fallback (rare)
  }
  __syncthreads();

  int size = end - beg;
  if (size > SCAP) size = SCAP;
  for (int i = threadIdx.x; i < size; i += 1024) colsrc[beg + i] = staged[i];
}

// ---------------------------------------------------------------------------
// gather1: 8 lanes/node; 16B requests. fp32 accum; fused mean+xr1+b1+ELU
// -> hb (bf16 table ONLY; fp32 h dropped — out path now reads hb).
// ---------------------------------------------------------------------------
__global__ __launch_bounds__(256) void gather1_kernel(
    const int* __restrict__ rowptr, const int* __restrict__ colsrc,
    const uint4* __restrict__ valb8, const float4* __restrict__ xr14,
    const float* __restrict__ b1, uint4* __restrict__ hb8) {
  int t = blockIdx.x * 256 + threadIdx.x;
  int n = t >> 3;
  if (n >= N_NODES) return;
  int d = t & 1;
  int p = (t >> 1) & 3;
  int beg = rowptr[n], end = rowptr[n + 1];

  float a[8] = {0.f, 0.f, 0.f, 0.f, 0.f, 0.f, 0.f, 0.f};
  int bA = (beg + 3) & ~3;
  int eA = end & ~3;
  if (bA > eA) {
    if (p == 0)
      for (int j = beg; j < end; ++j) accum8(valb8[colsrc[j] * 2 + d], a);
  } else {
    if (p == 0) {
      for (int j = beg; j < bA; ++j) accum8(valb8[colsrc[j] * 2 + d], a);
    } else if (p == 3) {
      for (int j = eA; j < end; ++j) accum8(valb8[colsrc[j] * 2 + d], a);
    }
    float a1[8] = {0.f, 0.f, 0.f, 0.f, 0.f, 0.f, 0.f, 0.f};
    int j = bA + p * 4;
    for (; j + 20 <= eA; j += 32) {
      v4i c0 = __builtin_nontemporal_load((const v4i*)(colsrc + j));
      v4i c1 = __builtin_nontemporal_load((const v4i*)(colsrc + j + 16));
      uint4 w0 = valb8[c0.x * 2 + d];
      uint4 w1 = valb8[c0.y * 2 + d];
      uint4 w2 = valb8[c0.z * 2 + d];
      uint4 w3 = valb8[c0.w * 2 + d];
      uint4 w4 = valb8[c1.x * 2 + d];
      uint4 w5 = valb8[c1.y * 2 + d];
      uint4 w6 = valb8[c1.z * 2 + d];
      uint4 w7 = valb8[c1.w * 2 + d];
      accum8(w0, a);
      accum8(w1, a1);
      accum8(w2, a);
      accum8(w3, a1);
      accum8(w4, a);
      accum8(w5, a1);
      accum8(w6, a);
      accum8(w7, a1);
    }
    for (; j + 4 <= eA; j += 16) {
      v4i c0 = __builtin_nontemporal_load((const v4i*)(colsrc + j));
      accum8(valb8[c0.x * 2 + d], a);
      accum8(valb8[c0.y * 2 + d], a1);
      accum8(valb8[c0.z * 2 + d], a);
      accum8(valb8[c0.w * 2 + d], a1);
    }
#pragma unroll
    for (int k = 0; k < 8; ++k) a[k] += a1[k];
  }

#pragma unroll
  for (int k = 0; k < 8; ++k) {
    a[k] += __shfl_xor(a[k], 2);
    a[k] += __shfl_xor(a[k], 4);
  }
  if (p) return;

  float inv = 1.0f / fmaxf((float)(end - beg), 1.0f);
  float4 r0 = xr14[n * 4 + 2 * d];
  float4 r1 = xr14[n * 4 + 2 * d + 1];
  const float4* bb = (const float4*)b1;
  float4 bb0 = bb[2 * d], bb1 = bb[2 * d + 1];
  float o[8];
  o[0] = a[0] * inv + r0.x + bb0.x;
  o[1] = a[1] * inv + r0.y + bb0.y;
  o[2] = a[2] * inv + r0.z + bb0.z;
  o[3] = a[3] * inv + r0.w + bb0.w;
  o[4] = a[4] * inv + r1.x + bb1.x;
  o[5] = a[5] * inv + r1.y + bb1.y;
  o[6] = a[6] * inv + r1.z + bb1.z;
  o[7] = a[7] * inv + r1.w + bb1.w;
#pragma unroll
  for (int k = 0; k < 8; ++k) o[k] = (o[k] > 0.f) ? o[k] : expm1f(o[k]);
  uint4 pk;
  pk.x = (unsigned)f2b(o[0]) | ((unsigned)f2b(o[1]) << 16);
  pk.y = (unsigned)f2b(o[2]) | ((unsigned)f2b(o[3]) << 16);
  pk.z = (unsigned)f2b(o[4]) | ((unsigned)f2b(o[5]) << 16);
  pk.w = (unsigned)f2b(o[6]) | ((unsigned)f2b(o[7]) << 16);
  hb8[n * 2 + d] = pk;
}

// ---------------------------------------------------------------------------
// R18 g2out: FUSED gather2 + out. Gather phase identical to gather2 (8 lanes
// per node over hb); mean agg goes to LDS (not global). Then per block
// (32 nodes): logits = agg@W2[1] + h@root2 + b2 (h = hb bf16 row, staged in
// LDS), log_softmax via 8-thread shfl reduce, store. Kills the 12.8MB agg2n
// round-trip + one dispatch.
// ---------------------------------------------------------------------------
__global__ __launch_bounds__(256) void g2out_kernel(
    const int* __restrict__ rowptr, const int* __restrict__ colsrc,
    const uint4* __restrict__ valb8, const unsigned* __restrict__ hbu,
    const float* __restrict__ W2, const float* __restrict__ root2,
    const float* __restrict__ b2v, float* __restrict__ out) {
  __shared__ float aggl[32][17];
  __shared__ float hl[32][17];
  __shared__ float Wl[HID * NCLS];
  __shared__ float Rl[HID * NCLS];
  __shared__ float Bl[NCLS];

  int tid = threadIdx.x;
  for (int i = tid; i < HID * NCLS; i += 256) {
    Wl[i] = W2[HID * NCLS + i];
    Rl[i] = root2[i];
  }
  if (tid < NCLS) Bl[tid] = b2v[tid];
  {
    // stage this block's 32 hb rows (bf16) as fp32: 256 uints = 512 values
    unsigned u = hbu[(size_t)blockIdx.x * 256 + tid];
    union { unsigned u; float f; } lo, hi;
    lo.u = u << 16;
    hi.u = u & 0xFFFF0000u;
    int nl = tid >> 3, uu = tid & 7;
    hl[nl][uu * 2] = lo.f;
    hl[nl][uu * 2 + 1] = hi.f;
  }

  // ---- gather phase (grid exact: 3125*32 == N_NODES) ----
  int nl = tid >> 3;
  int n = blockIdx.x * 32 + nl;
  int d = tid & 1;
  int p = (tid >> 1) & 3;
  int beg = rowptr[n], end = rowptr[n + 1];

  float a[8] = {0.f, 0.f, 0.f, 0.f, 0.f, 0.f, 0.f, 0.f};
  int bA = (beg + 3) & ~3;
  int eA = end & ~3;
  if (bA > eA) {
    if (p == 0)
      for (int j = beg; j < end; ++j) accum8(valb8[colsrc[j] * 2 + d], a);
  } else {
    if (p == 0) {
      for (int j = beg; j < bA; ++j) accum8(valb8[colsrc[j] * 2 + d], a);
    } else if (p == 3) {
      for (int j = eA; j < end; ++j) accum8(valb8[colsrc[j] * 2 + d], a);
    }
    float a1[8] = {0.f, 0.f, 0.f, 0.f, 0.f, 0.f, 0.f, 0.f};
    int j = bA + p * 4;
    for (; j + 20 <= eA; j += 32) {
      v4i c0 = __builtin_nontemporal_load((const v4i*)(colsrc + j));
      v4i c1 = __builtin_nontemporal_load((const v4i*)(colsrc + j + 16));
      uint4 w0 = valb8[c0.x * 2 + d];
      uint4 w1 = valb8[c0.y * 2 + d];
      uint4 w2 = valb8[c0.z * 2 + d];
      uint4 w3 = valb8[c0.w * 2 + d];
      uint4 w4 = valb8[c1.x * 2 + d];
      uint4 w5 = valb8[c1.y * 2 + d];
      uint4 w6 = valb8[c1.z * 2 + d];
      uint4 w7 = valb8[c1.w * 2 + d];
      accum8(w0, a);
      accum8(w1, a1);
      accum8(w2, a);
      accum8(w3, a1);
      accum8(w4, a);
      accum8(w5, a1);
      accum8(w6, a);
      accum8(w7, a1);
    }
    for (; j + 4 <= eA; j += 16) {
      v4i c0 = __builtin_nontemporal_load((const v4i*)(colsrc + j));
      accum8(valb8[c0.x * 2 + d], a);
      accum8(valb8[c0.y * 2 + d], a1);
      accum8(valb8[c0.z * 2 + d], a);
      accum8(valb8[c0.w * 2 + d], a1);
    }
#pragma unroll
    for (int k = 0; k < 8; ++k) a[k] += a1[k];
  }

#pragma unroll
  for (int k = 0; k < 8; ++k) {
    a[k] += __shfl_xor(a[k], 2);
    a[k] += __shfl_xor(a[k], 4);
  }
  if (p == 0) {
    float inv = 1.0f / fmaxf((float)(end - beg), 1.0f);
#pragma unroll
    for (int k = 0; k < 8; ++k) aggl[nl][d * 8 + k] = a[k] * inv;
  }
  __syncthreads();

  // ---- out phase: 8 threads/node, 5 classes each ----
  int q = tid & 7;
  float lg[5];
#pragma unroll
  for (int jj = 0; jj < 5; ++jj) lg[jj] = Bl[q * 5 + jj];
  for (int c = 0; c < HID; ++c) {
    float ac = aggl[nl][c];
    float hc = hl[nl][c];
    const float* wrow = Wl + c * NCLS + q * 5;
    const float* rrow = Rl + c * NCLS + q * 5;
#pragma unroll
    for (int jj = 0; jj < 5; ++jj) lg[jj] += ac * wrow[jj] + hc * rrow[jj];
  }
  float m = lg[0];
#pragma unroll
  for (int jj = 1; jj < 5; ++jj) m = fmaxf(m, lg[jj]);
  m = fmaxf(m, __shfl_xor(m, 1));
  m = fmaxf(m, __shfl_xor(m, 2));
  m = fmaxf(m, __shfl_xor(m, 4));
  float s = 0.f;
#pragma unroll
  for (int jj = 0; jj < 5; ++jj) s += expf(lg[jj] - m);
  s += __shfl_xor(s, 1);
  s += __shfl_xor(s, 2);
  s += __shfl_xor(s, 4);
  float lse = m + logf(s);
  float* op = out + (size_t)n * NCLS + q * 5;
#pragma unroll
  for (int jj = 0; jj < 5; ++jj) op[jj] = lg[jj] - lse;
}

extern "C" void kernel_launch(void* const* d_in, const int* in_sizes, int n_in,
                              void* d_out, int out_size, void* d_ws,
                              size_t ws_size, hipStream_t stream) {
  const float* x = (const float*)d_in[0];
  const int* ei = (const int*)d_in[1];  // (2, E): src row then dst row
  const float* W1 = (const float*)d_in[2];
  const float* root1 = (const float*)d_in[3];
  const float* b1 = (const float*)d_in[4];
  const float* W2 = (const float*)d_in[5];
  const float* root2 = (const float*)d_in[6];
  const float* b2v = (const float*)d_in[7];
  float* out = (float*)d_out;

  const int* src = ei;
  const int* dstp = ei + NEDGE;

  // workspace (bytes):
  // [bcnt 2K][boff 2K][gcursor 2K][rowptr (N+4)*4][recs E*4][colsrc E*4]
  // [xw1b 16N*2][xr1 16N*4][hb 16N*2]
  char* w = (char*)d_ws;
  int* bcnt = (int*)w;           w += 2048;
  int* boff = (int*)w;           w += 2048;
  int* gcursor = (int*)w;        w += 2048;
  int* rowptr = (int*)w;         w += (size_t)(N_NODES + 4) * 4;
  unsigned* recs = (unsigned*)w; w += (size_t)NEDGE * 4;
  int* colsrc = (int*)w;         w += (size_t)NEDGE * 4;
  unsigned* xw1b = (unsigned*)w; w += (size_t)N_NODES * HID * 2;
  float* xr1 = (float*)w;        w += (size_t)N_NODES * HID * 4;
  unsigned short* hb = (unsigned short*)w; w += (size_t)N_NODES * HID * 2;

  hipMemsetAsync(bcnt, 0, 2048, stream);

  histB_kernel<<<NCHUNK, 512, 0, stream>>>(dstp, bcnt);
  scan_kernel<<<1, 512, 0, stream>>>(bcnt, boff, gcursor, rowptr);
  mid_kernel<<<NCHUNK + PROJB, 512, 0, stream>>>(src, dstp, gcursor, recs, x,
                                                 W1, root1, xw1b, xr1);
  sortB_kernel<<<NBUCK, 1024, 0, stream>>>(boff, recs, rowptr, colsrc);
  gather1_kernel<<<(N_NODES * 8 + 255) / 256, 256, 0, stream>>>(
      rowptr, colsrc, (const uint4*)xw1b, (const float4*)xr1, b1, (uint4*)hb);
  g2out_kernel<<<N_NODES / 32, 256, 0, stream>>>(
      rowptr, colsrc, (const uint4*)hb, (const unsigned*)hb, W2, root2, b2v,
      out);
}